// Round 1
// baseline (12089.586 us; speedup 1.0000x reference)
//
#include <hip/hip_runtime.h>
#include <hip/hip_bf16.h>

#define NC 4096
#define GG 1024
#define DM 128
#define HH 4
#define HDIM 32
#define FF 512
#define LL 2
#define NHCI 2
#define LS2 (100.0f*100.0f)

enum { E_NONE=0, E_BIAS, E_RELU, E_TANH, E_BIASRES, E_SIGSP, E_ACC };

#define BM 128
#define BN 64
#define BK 16

template<int EPI, bool TB>
__launch_bounds__(256)
__global__ void gemm_k(const float* __restrict__ A, int lda,
                       const float* __restrict__ B, int ldb,
                       const float* __restrict__ bias,
                       const float* __restrict__ res, int ldres,
                       float* __restrict__ C, int ldc,
                       int M, int N, int K, float alpha,
                       const float* __restrict__ spd, int ldspd,
                       const int* __restrict__ flag)
{
    if (flag && *flag == 0) return;
    __shared__ __align__(16) float As[BK][BM+4];
    __shared__ __align__(16) float Bs[BK][BN+4];
    const int bm = blockIdx.y * BM, bn = blockIdx.x * BN;
    const int tid = threadIdx.x;
    const int tx = tid & 15;   // col group (4 cols)
    const int ty = tid >> 4;   // row group (8 rows)
    float acc[8][4];
    #pragma unroll
    for (int i=0;i<8;i++)
        #pragma unroll
        for (int j=0;j<4;j++) acc[i][j]=0.f;

    for (int k0 = 0; k0 < K; k0 += BK) {
        // A tile: BM x BK (2048 elems, 8 per thread)
        #pragma unroll
        for (int t = 0; t < (BM*BK)/256; ++t) {
            int i = tid + t*256;
            int m = i >> 4, kk = i & 15;
            int gm = bm + m, gk = k0 + kk;
            As[kk][m] = (gm < M && gk < K) ? A[(size_t)gm*lda + gk] : 0.f;
        }
        // B tile: BK x BN (1024 elems, 4 per thread)
        #pragma unroll
        for (int t = 0; t < (BN*BK)/256; ++t) {
            int i = tid + t*256;
            if (!TB) {
                int kk = i >> 6, n = i & 63;
                int gk = k0 + kk, gn = bn + n;
                Bs[kk][n] = (gk < K && gn < N) ? B[(size_t)gk*ldb + gn] : 0.f;
            } else {
                int n = i >> 4, kk = i & 15;
                int gn = bn + n, gk = k0 + kk;
                Bs[kk][n] = (gn < N && gk < K) ? B[(size_t)gn*ldb + gk] : 0.f;
            }
        }
        __syncthreads();
        #pragma unroll
        for (int kk = 0; kk < BK; ++kk) {
            float4 a0 = *(const float4*)&As[kk][ty*8];
            float4 a1 = *(const float4*)&As[kk][ty*8+4];
            float4 b0 = *(const float4*)&Bs[kk][tx*4];
            float a[8] = {a0.x,a0.y,a0.z,a0.w,a1.x,a1.y,a1.z,a1.w};
            float b[4] = {b0.x,b0.y,b0.z,b0.w};
            #pragma unroll
            for (int i=0;i<8;i++)
                #pragma unroll
                for (int j=0;j<4;j++)
                    acc[i][j] = fmaf(a[i], b[j], acc[i][j]);
        }
        __syncthreads();
    }
    #pragma unroll
    for (int i=0;i<8;i++){
        int gm = bm + ty*8 + i;
        if (gm >= M) break;
        #pragma unroll
        for (int j=0;j<4;j++){
            int gn = bn + tx*4 + j;
            if (gn >= N) continue;
            float v = acc[i][j] * alpha;
            if (EPI==E_BIAS || EPI==E_RELU || EPI==E_TANH || EPI==E_BIASRES) v += bias[gn];
            if (EPI==E_RELU) v = fmaxf(v, 0.f);
            if (EPI==E_TANH) v = tanhf(v);
            if (EPI==E_BIASRES) v += res[(size_t)gm*ldres + gn];
            if (EPI==E_SIGSP) {
                v = 1.f/(1.f+expf(-v));
                v *= expf(spd[(size_t)gm*ldspd + gn] * (-1.f/LS2));
            }
            size_t ci = (size_t)gm*ldc + gn;
            if (EPI==E_ACC) C[ci] += v; else C[ci] = v;
        }
    }
}

// quality[i] = dot(Tq[i, 0:64], w) + b2
__global__ void qualify2_k(const float* __restrict__ Tq, const float* __restrict__ w,
                           const float* __restrict__ b2, float* __restrict__ quality)
{
    int row = blockIdx.x, lane = threadIdx.x;
    float v = Tq[row*64 + lane] * w[lane];
    #pragma unroll
    for (int o=32;o>0;o>>=1) v += __shfl_down(v, o);
    if (lane == 0) quality[row] = v + b2[0];
}

// sq[i] = sum_d h[i,d]^2   (D=128, block=64)
__global__ void rownorm_k(const float* __restrict__ h, float* __restrict__ sq)
{
    int row = blockIdx.x, lane = threadIdx.x;
    float x0 = h[row*DM + lane], x1 = h[row*DM + lane + 64];
    float v = x0*x0 + x1*x1;
    #pragma unroll
    for (int o=32;o>0;o>>=1) v += __shfl_down(v, o);
    v = __shfl(v, 0);
    if (lane == 0) sq[row] = v;
}

// h = LN(h + t; g, b) over D=128, block=64
__global__ void add_ln_k(float* __restrict__ h, const float* __restrict__ t,
                         const float* __restrict__ g, const float* __restrict__ b)
{
    int row = blockIdx.x, lane = threadIdx.x;
    float x0 = h[row*DM + lane]      + t[row*DM + lane];
    float x1 = h[row*DM + lane + 64] + t[row*DM + lane + 64];
    float s = x0 + x1, ss = x0*x0 + x1*x1;
    #pragma unroll
    for (int o=32;o>0;o>>=1) { s += __shfl_down(s, o); ss += __shfl_down(ss, o); }
    s = __shfl(s, 0); ss = __shfl(ss, 0);
    float mean = s * (1.f/128.f);
    float var  = ss * (1.f/128.f) - mean*mean;
    float inv  = rsqrtf(var + 1e-5f);
    h[row*DM + lane]      = g[lane]      * (x0 - mean) * inv + b[lane];
    h[row*DM + lane + 64] = g[lane + 64] * (x1 - mean) * inv + b[lane + 64];
}

__launch_bounds__(256)
__global__ void softmax_rows_k(float* __restrict__ S, int W)
{
    __shared__ float red[4];
    size_t row = blockIdx.x;
    float* p = S + row * (size_t)W;
    int tid = threadIdx.x;
    float m = -3.0e38f;
    for (int j = tid; j < W; j += 256) m = fmaxf(m, p[j]);
    #pragma unroll
    for (int o=32;o>0;o>>=1) m = fmaxf(m, __shfl_down(m, o));
    if ((tid & 63) == 0) red[tid >> 6] = m;
    __syncthreads();
    m = fmaxf(fmaxf(red[0], red[1]), fmaxf(red[2], red[3]));
    __syncthreads();
    float sum = 0.f;
    for (int j = tid; j < W; j += 256) { float e = expf(p[j] - m); p[j] = e; sum += e; }
    #pragma unroll
    for (int o=32;o>0;o>>=1) sum += __shfl_down(sum, o);
    if ((tid & 63) == 0) red[tid >> 6] = sum;
    __syncthreads();
    sum = red[0] + red[1] + red[2] + red[3];
    float inv = 1.f / sum;
    for (int j = tid; j < W; j += 256) p[j] *= inv;
}

// S holds Gram(emb). Turn each row into softmax(-dist + quality[j]).
__launch_bounds__(256)
__global__ void dist_softmax_k(float* __restrict__ S, const float* __restrict__ sqv,
                               const float* __restrict__ qual, int W)
{
    __shared__ float red[4];
    size_t row = blockIdx.x;
    float* p = S + row * (size_t)W;
    int tid = threadIdx.x;
    float sqi = sqv[row];
    float m = -3.0e38f;
    for (int j = tid; j < W; j += 256) {
        float d2 = fmaxf(sqi + sqv[j] - 2.f * p[j], 0.f);
        float lg = -sqrtf(d2) + qual[j];
        m = fmaxf(m, lg);
    }
    #pragma unroll
    for (int o=32;o>0;o>>=1) m = fmaxf(m, __shfl_down(m, o));
    if ((tid & 63) == 0) red[tid >> 6] = m;
    __syncthreads();
    m = fmaxf(fmaxf(red[0], red[1]), fmaxf(red[2], red[3]));
    __syncthreads();
    float sum = 0.f;
    for (int j = tid; j < W; j += 256) {
        float d2 = fmaxf(sqi + sqv[j] - 2.f * p[j], 0.f);
        float lg = -sqrtf(d2) + qual[j];
        float e = expf(lg - m);
        p[j] = e;
        sum += e;
    }
    #pragma unroll
    for (int o=32;o>0;o>>=1) sum += __shfl_down(sum, o);
    if ((tid & 63) == 0) red[tid >> 6] = sum;
    __syncthreads();
    sum = red[0] + red[1] + red[2] + red[3];
    float inv = 1.f / sum;
    for (int j = tid; j < W; j += 256) p[j] *= inv;
}

__global__ void copy_k(float* __restrict__ dst, const float* __restrict__ src, size_t n)
{
    size_t i = blockIdx.x * (size_t)blockDim.x + threadIdx.x;
    if (i < n) dst[i] = src[i];
}

static void launch_gemm(int epi, bool tb,
                        const float* A, int lda, const float* B, int ldb,
                        const float* bias, const float* res, int ldres,
                        float* C, int ldc, int M, int Nn, int K, float alpha,
                        const float* spd, int ldspd, const int* flag, hipStream_t s)
{
    dim3 grid((Nn + BN - 1) / BN, (M + BM - 1) / BM), block(256);
#define GL(E,T) gemm_k<E,T><<<grid,block,0,s>>>(A,lda,B,ldb,bias,res,ldres,C,ldc,M,Nn,K,alpha,spd,ldspd,flag)
    if (tb) {
        if (epi == E_NONE)       GL(E_NONE,  true);
        else if (epi == E_SIGSP) GL(E_SIGSP, true);
    } else {
        switch (epi) {
            case E_NONE:    GL(E_NONE,    false); break;
            case E_BIAS:    GL(E_BIAS,    false); break;
            case E_RELU:    GL(E_RELU,    false); break;
            case E_TANH:    GL(E_TANH,    false); break;
            case E_BIASRES: GL(E_BIASRES, false); break;
            case E_ACC:     GL(E_ACC,     false); break;
        }
    }
#undef GL
}

extern "C" void kernel_launch(void* const* d_in, const int* in_sizes, int n_in,
                              void* d_out, int out_size, void* d_ws, size_t ws_size,
                              hipStream_t stream)
{
    const float* raw   = (const float*)d_in[0];
    const float* spd   = (const float*)d_in[1];
    const float* dn_W1 = (const float*)d_in[2];
    const float* dn_b1 = (const float*)d_in[3];
    const float* dn_W2 = (const float*)d_in[4];
    const float* dn_b2 = (const float*)d_in[5];
    const float* q_W1  = (const float*)d_in[6];
    const float* q_b1  = (const float*)d_in[7];
    const float* q_W2  = (const float*)d_in[8];
    const float* q_b2  = (const float*)d_in[9];
    const float* e_Win = (const float*)d_in[10];
    const float* e_bin = (const float*)d_in[11];
    const float* Wq    = (const float*)d_in[12];
    const float* Wk    = (const float*)d_in[13];
    const float* Wv    = (const float*)d_in[14];
    const float* Wo    = (const float*)d_in[15];
    const float* bq    = (const float*)d_in[16];
    const float* bk    = (const float*)d_in[17];
    const float* bv    = (const float*)d_in[18];
    const float* bo    = (const float*)d_in[19];
    const float* ln1_g = (const float*)d_in[20];
    const float* ln1_b = (const float*)d_in[21];
    const float* ln2_g = (const float*)d_in[22];
    const float* ln2_b = (const float*)d_in[23];
    const float* f_W1  = (const float*)d_in[24];
    const float* f_b1  = (const float*)d_in[25];
    const float* f_W2  = (const float*)d_in[26];
    const float* f_b2  = (const float*)d_in[27];
    const float* ci_T  = (const float*)d_in[28];
    const float* ci_G  = (const float*)d_in[29];
    const int*   interact = (const int*)d_in[30];

    float* out = (float*)d_out;
    float* ws = (float*)d_ws;
    size_t off = 0;
    auto alloc = [&](size_t n) { float* p = ws + off; off += n; return p; };
    float* S        = alloc((size_t)NC * NC);   // 67 MB: scores / gram / sim / CI
    float* denoised = alloc((size_t)NC * GG);
    float* smoothed = alloc((size_t)NC * GG);
    float* U        = alloc((size_t)NC * GG);
    float* T1       = alloc((size_t)NC * FF);   // denoise mid / ffn mid
    float* Tq       = alloc((size_t)NC * 64);
    float* quality  = alloc((size_t)NC);
    float* h        = alloc((size_t)NC * DM);
    float* qb       = alloc((size_t)NC * DM);
    float* kb       = alloc((size_t)NC * DM);
    float* vb       = alloc((size_t)NC * DM);
    float* ob       = alloc((size_t)NC * DM);
    float* t2       = alloc((size_t)NC * DM);
    float* Temb     = alloc((size_t)NC * DM);
    float* sqbuf    = alloc((size_t)NC);
    (void)ws_size; (void)n_in; (void)in_sizes; (void)out_size;

    const float inv_sqrt_hd = 0.17677669529663687f; // 1/sqrt(32)

    // --- CellDenoise ---
    launch_gemm(E_RELU, false, raw, GG, dn_W1, FF, dn_b1, nullptr, 0,
                T1, FF, NC, FF, GG, 1.f, nullptr, 0, nullptr, stream);
    launch_gemm(E_BIASRES, false, T1, FF, dn_W2, GG, dn_b2, raw, GG,
                denoised, GG, NC, GG, FF, 1.f, nullptr, 0, nullptr, stream);
    // --- CellQualify ---
    launch_gemm(E_TANH, false, raw, GG, q_W1, 64, q_b1, nullptr, 0,
                Tq, 64, NC, 64, GG, 1.f, nullptr, 0, nullptr, stream);
    qualify2_k<<<NC, 64, 0, stream>>>(Tq, q_W2, q_b2, quality);
    // --- CellEmbed input proj ---
    launch_gemm(E_BIAS, false, raw, GG, e_Win, DM, e_bin, nullptr, 0,
                h, DM, NC, DM, GG, 1.f, nullptr, 0, nullptr, stream);
    // --- Transformer layers ---
    for (int l = 0; l < LL; ++l) {
        launch_gemm(E_BIAS, false, h, DM, Wq + (size_t)l*DM*DM, DM, bq + l*DM, nullptr, 0,
                    qb, DM, NC, DM, DM, 1.f, nullptr, 0, nullptr, stream);
        launch_gemm(E_BIAS, false, h, DM, Wk + (size_t)l*DM*DM, DM, bk + l*DM, nullptr, 0,
                    kb, DM, NC, DM, DM, 1.f, nullptr, 0, nullptr, stream);
        launch_gemm(E_BIAS, false, h, DM, Wv + (size_t)l*DM*DM, DM, bv + l*DM, nullptr, 0,
                    vb, DM, NC, DM, DM, 1.f, nullptr, 0, nullptr, stream);
        for (int hd = 0; hd < HH; ++hd) {
            launch_gemm(E_NONE, true, qb + hd*HDIM, DM, kb + hd*HDIM, DM, nullptr, nullptr, 0,
                        S, NC, NC, NC, HDIM, inv_sqrt_hd, nullptr, 0, nullptr, stream);
            softmax_rows_k<<<NC, 256, 0, stream>>>(S, NC);
            launch_gemm(E_NONE, false, S, NC, vb + hd*HDIM, DM, nullptr, nullptr, 0,
                        ob + hd*HDIM, DM, NC, HDIM, NC, 1.f, nullptr, 0, nullptr, stream);
        }
        launch_gemm(E_BIAS, false, ob, DM, Wo + (size_t)l*DM*DM, DM, bo + l*DM, nullptr, 0,
                    t2, DM, NC, DM, DM, 1.f, nullptr, 0, nullptr, stream);
        add_ln_k<<<NC, 64, 0, stream>>>(h, t2, ln1_g + l*DM, ln1_b + l*DM);
        launch_gemm(E_RELU, false, h, DM, f_W1 + (size_t)l*DM*FF, FF, f_b1 + l*FF, nullptr, 0,
                    T1, FF, NC, FF, DM, 1.f, nullptr, 0, nullptr, stream);
        launch_gemm(E_BIAS, false, T1, FF, f_W2 + (size_t)l*FF*DM, DM, f_b2 + l*DM, nullptr, 0,
                    t2, DM, NC, DM, FF, 1.f, nullptr, 0, nullptr, stream);
        add_ln_k<<<NC, 64, 0, stream>>>(h, t2, ln2_g + l*DM, ln2_b + l*DM);
    }
    // --- CellSmooth ---
    rownorm_k<<<NC, 64, 0, stream>>>(h, sqbuf);
    launch_gemm(E_NONE, true, h, DM, h, DM, nullptr, nullptr, 0,
                S, NC, NC, NC, DM, 1.f, nullptr, 0, nullptr, stream);
    dist_softmax_k<<<NC, 256, 0, stream>>>(S, sqbuf, quality, NC);
    launch_gemm(E_NONE, false, S, NC, denoised, GG, nullptr, nullptr, 0,
                smoothed, GG, NC, GG, NC, 1.f, nullptr, 0, nullptr, stream);
    copy_k<<<(int)(((size_t)NC*GG + 255)/256), 256, 0, stream>>>(out, smoothed, (size_t)NC*GG);
    // --- CellInteract (device-side gated on interact flag) ---
    for (int hh = 0; hh < NHCI; ++hh) {
        launch_gemm(E_NONE, false, h, DM, ci_T + (size_t)hh*DM*DM, DM, nullptr, nullptr, 0,
                    Temb, DM, NC, DM, DM, 1.f, nullptr, 0, interact, stream);
        launch_gemm(E_SIGSP, true, Temb, DM, h, DM, nullptr, nullptr, 0,
                    S, NC, NC, NC, DM, 1.f, spd, NC, interact, stream);
        launch_gemm(E_NONE, false, S, NC, smoothed, GG, nullptr, nullptr, 0,
                    U, GG, NC, GG, NC, 1.f, nullptr, 0, interact, stream);
        launch_gemm(E_ACC, false, U, GG, ci_G + (size_t)hh*GG*GG, GG, nullptr, nullptr, 0,
                    out, GG, NC, GG, GG, 1.0f/1024.f, nullptr, 0, interact, stream);
    }
}

// Round 2
// 7875.821 us; speedup vs baseline: 1.5350x; 1.5350x over previous
//
#include <hip/hip_runtime.h>
#include <hip/hip_bf16.h>

#define NC 4096
#define GG 1024
#define DM 128
#define HDIM 32
#define FF 512
#define LL 2
#define NHCI 2
#define LS2 (100.0f*100.0f)

typedef __bf16 bf16x8 __attribute__((ext_vector_type(8)));
typedef __bf16 bf16x4 __attribute__((ext_vector_type(4)));
typedef float  f32x4  __attribute__((ext_vector_type(4)));

// ================= fp32 fallback GEMM (round-1, proven) =================
enum { E_NONE=0, E_TANH };
#define BM 128
#define BN 64
#define BK 16

template<int EPI>
__launch_bounds__(256)
__global__ void gemm_k(const float* __restrict__ A, int lda,
                       const float* __restrict__ B, int ldb,
                       const float* __restrict__ bias,
                       float* __restrict__ C, int ldc,
                       int M, int N, int K, float alpha)
{
    __shared__ __align__(16) float As[BK][BM+4];
    __shared__ __align__(16) float Bs[BK][BN+4];
    const int bm = blockIdx.y * BM, bn = blockIdx.x * BN;
    const int tid = threadIdx.x;
    const int tx = tid & 15;
    const int ty = tid >> 4;
    float acc[8][4];
    #pragma unroll
    for (int i=0;i<8;i++)
        #pragma unroll
        for (int j=0;j<4;j++) acc[i][j]=0.f;

    for (int k0 = 0; k0 < K; k0 += BK) {
        #pragma unroll
        for (int t = 0; t < (BM*BK)/256; ++t) {
            int i = tid + t*256;
            int m = i >> 4, kk = i & 15;
            int gm = bm + m, gk = k0 + kk;
            As[kk][m] = (gm < M && gk < K) ? A[(size_t)gm*lda + gk] : 0.f;
        }
        #pragma unroll
        for (int t = 0; t < (BN*BK)/256; ++t) {
            int i = tid + t*256;
            int kk = i >> 6, n = i & 63;
            int gk = k0 + kk, gn = bn + n;
            Bs[kk][n] = (gk < K && gn < N) ? B[(size_t)gk*ldb + gn] : 0.f;
        }
        __syncthreads();
        #pragma unroll
        for (int kk = 0; kk < BK; ++kk) {
            float4 a0 = *(const float4*)&As[kk][ty*8];
            float4 a1 = *(const float4*)&As[kk][ty*8+4];
            float4 b0 = *(const float4*)&Bs[kk][tx*4];
            float a[8] = {a0.x,a0.y,a0.z,a0.w,a1.x,a1.y,a1.z,a1.w};
            float b[4] = {b0.x,b0.y,b0.z,b0.w};
            #pragma unroll
            for (int i=0;i<8;i++)
                #pragma unroll
                for (int j=0;j<4;j++)
                    acc[i][j] = fmaf(a[i], b[j], acc[i][j]);
        }
        __syncthreads();
    }
    #pragma unroll
    for (int i=0;i<8;i++){
        int gm = bm + ty*8 + i;
        if (gm >= M) break;
        #pragma unroll
        for (int j=0;j<4;j++){
            int gn = bn + tx*4 + j;
            if (gn >= N) continue;
            float v = acc[i][j] * alpha;
            if (EPI==E_TANH) v = tanhf(v + bias[gn]);
            C[(size_t)gm*ldc + gn] = v;
        }
    }
}

// ================= bf16 MFMA GEMM (m97 structure) =================
// C[M][N] = A[M][K](bf16,row-major) x BT[N][K](bf16,row-major)^T, fp32 accum.
// Tile 128x128, BK=32, 4 waves (2x2), wave tile 64x64 = 4x4 fragments of 16x16x32.
enum { MM_NONE=0, MM_BIAS, MM_BIAS_BOTH, MM_BIAS_B16, MM_RELU_B16, MM_B16,
       MM_BIASRES, MM_SIGSP_B16, MM_ACC };

template<int EM>
__launch_bounds__(256)
__global__ void mgemm_k(const __bf16* __restrict__ A, int lda,
                        const __bf16* __restrict__ BT, int ldb,
                        const float* __restrict__ bias,
                        const float* __restrict__ res, int ldres,
                        float* __restrict__ C, __bf16* __restrict__ Cb, int ldc,
                        int M, int N, int K, float alpha,
                        const float* __restrict__ spd,
                        const int* __restrict__ flag)
{
    if (flag && *flag == 0) return;
    __shared__ __align__(16) __bf16 As[128][32];   // 8 KB
    __shared__ __align__(16) __bf16 Bs[128][32];   // 8 KB
    const int tid  = threadIdx.x;
    const int lane = tid & 63;
    const int wid  = tid >> 6;
    const int wm = wid >> 1, wn = wid & 1;
    const int bm = blockIdx.y * 128, bn = blockIdx.x * 128;

    f32x4 acc[4][4];
    #pragma unroll
    for (int m=0;m<4;m++)
        #pragma unroll
        for (int n=0;n<4;n++) acc[m][n] = (f32x4){0.f,0.f,0.f,0.f};

    // staging: tile = 512 chunks of 16B (8 bf16). chunk c -> row c>>2, k-off (c&3)*8.
    const int c0 = wid*64 + lane, c1 = c0 + 256;
    const __bf16* ga0 = A  + (size_t)(bm + (c0>>2))*lda + ((c0&3)<<3);
    const __bf16* ga1 = A  + (size_t)(bm + (c1>>2))*lda + ((c1&3)<<3);
    const __bf16* gb0 = BT + (size_t)(bn + (c0>>2))*ldb + ((c0&3)<<3);
    const __bf16* gb1 = BT + (size_t)(bn + (c1>>2))*ldb + ((c1&3)<<3);
    // wave-uniform LDS dest bases (HW adds lane*16)
    auto* lA = (__attribute__((address_space(3))) __bf16*)&As[0][0];
    auto* lB = (__attribute__((address_space(3))) __bf16*)&Bs[0][0];
    auto* lA0 = (__attribute__((address_space(3))) void*)(lA + (size_t)(wid*64)*8);
    auto* lA1 = (__attribute__((address_space(3))) void*)(lA + (size_t)(256 + wid*64)*8);
    auto* lB0 = (__attribute__((address_space(3))) void*)(lB + (size_t)(wid*64)*8);
    auto* lB1 = (__attribute__((address_space(3))) void*)(lB + (size_t)(256 + wid*64)*8);

    const int r  = lane & 15;        // row within 16-block (A: M-row, B: N-col)
    const int kb = lane >> 4;        // k-subblock (8 elems each)
    const int arow = wm*64, brow = wn*64;

    for (int k0 = 0; k0 < K; k0 += 32) {
        __builtin_amdgcn_global_load_lds((const __attribute__((address_space(1))) void*)ga0, lA0, 16, 0, 0);
        __builtin_amdgcn_global_load_lds((const __attribute__((address_space(1))) void*)ga1, lA1, 16, 0, 0);
        __builtin_amdgcn_global_load_lds((const __attribute__((address_space(1))) void*)gb0, lB0, 16, 0, 0);
        __builtin_amdgcn_global_load_lds((const __attribute__((address_space(1))) void*)gb1, lB1, 16, 0, 0);
        ga0 += 32; ga1 += 32; gb0 += 32; gb1 += 32;
        __syncthreads();   // compiler drains vmcnt before barrier
        bf16x8 af[4], bfr[4];
        #pragma unroll
        for (int m=0;m<4;m++) af[m]  = *(const bf16x8*)&As[arow + m*16 + r][kb*8];
        #pragma unroll
        for (int n=0;n<4;n++) bfr[n] = *(const bf16x8*)&Bs[brow + n*16 + r][kb*8];
        #pragma unroll
        for (int m=0;m<4;m++)
            #pragma unroll
            for (int n=0;n<4;n++)
                acc[m][n] = __builtin_amdgcn_mfma_f32_16x16x32_bf16(af[m], bfr[n], acc[m][n], 0, 0, 0);
        __syncthreads();
    }

    // C/D layout: col = lane&15, row = (lane>>4)*4 + reg
    const int crow = (lane >> 4) * 4;
    const int ccol = lane & 15;
    #pragma unroll
    for (int m=0;m<4;m++) {
        #pragma unroll
        for (int n=0;n<4;n++) {
            const int gn = bn + wn*64 + n*16 + ccol;
            #pragma unroll
            for (int q=0;q<4;q++) {
                const int gm = bm + wm*64 + m*16 + crow + q;
                float v = acc[m][n][q] * alpha;
                if (EM==MM_BIAS || EM==MM_BIAS_BOTH || EM==MM_BIAS_B16 ||
                    EM==MM_RELU_B16 || EM==MM_BIASRES) v += bias[gn];
                if (EM==MM_RELU_B16) v = fmaxf(v, 0.f);
                if (EM==MM_BIASRES)  v += res[(size_t)gm*ldres + gn];
                if (EM==MM_SIGSP_B16) {
                    v = 1.f/(1.f + __expf(-v));
                    v *= __expf(spd[(size_t)gm*(size_t)N + gn] * (-1.f/LS2));
                }
                const size_t ci = (size_t)gm*ldc + gn;
                if (EM==MM_ACC) C[ci] += v;
                else if (EM==MM_NONE || EM==MM_BIAS || EM==MM_BIASRES) C[ci] = v;
                else if (EM==MM_BIAS_BOTH) { C[ci] = v; Cb[ci] = (__bf16)v; }
                else Cb[ci] = (__bf16)v;   // *_B16
            }
        }
    }
}

// ================= small kernels =================
__global__ void qualify2_k(const float* __restrict__ Tq, const float* __restrict__ w,
                           const float* __restrict__ b2, float* __restrict__ quality)
{
    int row = blockIdx.x, lane = threadIdx.x;
    float v = Tq[row*64 + lane] * w[lane];
    #pragma unroll
    for (int o=32;o>0;o>>=1) v += __shfl_down(v, o);
    if (lane == 0) quality[row] = v + b2[0];
}

__global__ void rownorm_k(const float* __restrict__ h, float* __restrict__ sq)
{
    int row = blockIdx.x, lane = threadIdx.x;
    float x0 = h[row*DM + lane], x1 = h[row*DM + lane + 64];
    float v = x0*x0 + x1*x1;
    #pragma unroll
    for (int o=32;o>0;o>>=1) v += __shfl_down(v, o);
    if (lane == 0) sq[row] = v;
}

// h = LN(h + t); writes fp32 h and bf16 hb
__global__ void add_ln_k(float* __restrict__ h, __bf16* __restrict__ hb,
                         const float* __restrict__ t,
                         const float* __restrict__ g, const float* __restrict__ b)
{
    int row = blockIdx.x, lane = threadIdx.x;
    float x0 = h[row*DM + lane]      + t[row*DM + lane];
    float x1 = h[row*DM + lane + 64] + t[row*DM + lane + 64];
    float s = x0 + x1, ss = x0*x0 + x1*x1;
    #pragma unroll
    for (int o=32;o>0;o>>=1) { s += __shfl_down(s, o); ss += __shfl_down(ss, o); }
    s = __shfl(s, 0); ss = __shfl(ss, 0);
    float mean = s * (1.f/128.f);
    float var  = ss * (1.f/128.f) - mean*mean;
    float inv  = rsqrtf(var + 1e-5f);
    float y0 = g[lane]      * (x0 - mean) * inv + b[lane];
    float y1 = g[lane + 64] * (x1 - mean) * inv + b[lane + 64];
    h[row*DM + lane]       = y0;  h[row*DM + lane + 64]  = y1;
    hb[row*DM + lane]      = (__bf16)y0;
    hb[row*DM + lane + 64] = (__bf16)y1;
}

// online softmax, fp32 in-place (2 reads + 1 write)
__launch_bounds__(256)
__global__ void softmax_rows_k(float* __restrict__ S, int W)
{
    __shared__ float sm[4], sl[4];
    size_t row = blockIdx.x;
    float* p = S + row * (size_t)W;
    int tid = threadIdx.x;
    float m = -3.0e38f, l = 0.f;
    for (int j = tid; j < W; j += 256) {
        float x = p[j];
        float mn = fmaxf(m, x);
        l = l * __expf(m - mn) + __expf(x - mn);
        m = mn;
    }
    #pragma unroll
    for (int o=32;o>0;o>>=1) {
        float m2 = __shfl_down(m, o), l2 = __shfl_down(l, o);
        float mn = fmaxf(m, m2);
        l = l * __expf(m - mn) + l2 * __expf(m2 - mn);
        m = mn;
    }
    if ((tid & 63) == 0) { sm[tid>>6] = m; sl[tid>>6] = l; }
    __syncthreads();
    m = sm[0]; l = sl[0];
    #pragma unroll
    for (int i=1;i<4;i++) {
        float mn = fmaxf(m, sm[i]);
        l = l * __expf(m - mn) + sl[i] * __expf(sm[i] - mn);
        m = mn;
    }
    float inv = 1.f / l;
    for (int j = tid; j < W; j += 256) p[j] = __expf(p[j] - m) * inv;
}

// gram fp32 -> sim bf16: softmax(-sqrt(max(sqi+sqj-2*gram,0)) + qual[j])
__launch_bounds__(256)
__global__ void dist_softmax_k(const float* __restrict__ Sg, const float* __restrict__ sqv,
                               const float* __restrict__ qual, __bf16* __restrict__ P, int W)
{
    __shared__ float sm[4], sl[4];
    size_t row = blockIdx.x;
    const float* p = Sg + row * (size_t)W;
    __bf16* po = P + row * (size_t)W;
    int tid = threadIdx.x;
    float sqi = sqv[row];
    float m = -3.0e38f, l = 0.f;
    for (int j = tid; j < W; j += 256) {
        float d2 = fmaxf(sqi + sqv[j] - 2.f * p[j], 0.f);
        float lg = -sqrtf(d2) + qual[j];
        float mn = fmaxf(m, lg);
        l = l * __expf(m - mn) + __expf(lg - mn);
        m = mn;
    }
    #pragma unroll
    for (int o=32;o>0;o>>=1) {
        float m2 = __shfl_down(m, o), l2 = __shfl_down(l, o);
        float mn = fmaxf(m, m2);
        l = l * __expf(m - mn) + l2 * __expf(m2 - mn);
        m = mn;
    }
    if ((tid & 63) == 0) { sm[tid>>6] = m; sl[tid>>6] = l; }
    __syncthreads();
    m = sm[0]; l = sl[0];
    #pragma unroll
    for (int i=1;i<4;i++) {
        float mn = fmaxf(m, sm[i]);
        l = l * __expf(m - mn) + sl[i] * __expf(sm[i] - mn);
        m = mn;
    }
    float inv = 1.f / l;
    for (int j = tid; j < W; j += 256) {
        float d2 = fmaxf(sqi + sqv[j] - 2.f * p[j], 0.f);
        float lg = -sqrtf(d2) + qual[j];
        po[j] = (__bf16)(__expf(lg - m) * inv);
    }
}

// fp32 [R][C] -> bf16 [C][R]
__global__ void tconv_k(const float* __restrict__ in, __bf16* __restrict__ out,
                        int R, int C, const int* __restrict__ flag)
{
    if (flag && *flag == 0) return;
    __shared__ float tile[32][33];
    int bc = blockIdx.x * 32, br = blockIdx.y * 32;
    int tx = threadIdx.x & 31, ty = threadIdx.x >> 5;   // 32 x 8
    #pragma unroll
    for (int i=0;i<4;i++)
        tile[ty + 8*i][tx] = in[(size_t)(br + ty + 8*i)*C + bc + tx];
    __syncthreads();
    #pragma unroll
    for (int i=0;i<4;i++)
        out[(size_t)(bc + ty + 8*i)*R + br + tx] = (__bf16)tile[tx][ty + 8*i];
}

// fp32 -> bf16, flat (n multiple of 4)
__global__ void conv_k(const float* __restrict__ in, __bf16* __restrict__ out, int n4)
{
    int i = blockIdx.x * 256 + threadIdx.x;
    if (i < n4) {
        float4 v = ((const float4*)in)[i];
        bf16x4 o = {(__bf16)v.x, (__bf16)v.y, (__bf16)v.z, (__bf16)v.w};
        ((bf16x4*)out)[i] = o;
    }
}

// ================= launchers =================
static void mg(int em, const __bf16* A, int lda, const __bf16* BT, int ldb,
               const float* bias, const float* res, int ldres,
               float* C, __bf16* Cb, int ldc, int M, int N, int K, float alpha,
               const float* spd, const int* flag, hipStream_t s)
{
    dim3 grid(N/128, M/128), block(256);
#define MGL(E) mgemm_k<E><<<grid,block,0,s>>>(A,lda,BT,ldb,bias,res,ldres,C,Cb,ldc,M,N,K,alpha,spd,flag)
    switch (em) {
        case MM_NONE:      MGL(MM_NONE);      break;
        case MM_BIAS:      MGL(MM_BIAS);      break;
        case MM_BIAS_BOTH: MGL(MM_BIAS_BOTH); break;
        case MM_BIAS_B16:  MGL(MM_BIAS_B16);  break;
        case MM_RELU_B16:  MGL(MM_RELU_B16);  break;
        case MM_B16:       MGL(MM_B16);       break;
        case MM_BIASRES:   MGL(MM_BIASRES);   break;
        case MM_SIGSP_B16: MGL(MM_SIGSP_B16); break;
        case MM_ACC:       MGL(MM_ACC);       break;
    }
#undef MGL
}

static void tc(const float* in, __bf16* out, int R, int C, const int* flag, hipStream_t s)
{
    dim3 grid(C/32, R/32), block(256);
    tconv_k<<<grid, block, 0, s>>>(in, out, R, C, flag);
}

extern "C" void kernel_launch(void* const* d_in, const int* in_sizes, int n_in,
                              void* d_out, int out_size, void* d_ws, size_t ws_size,
                              hipStream_t stream)
{
    const float* raw   = (const float*)d_in[0];
    const float* spd   = (const float*)d_in[1];
    const float* dn_W1 = (const float*)d_in[2];
    const float* dn_b1 = (const float*)d_in[3];
    const float* dn_W2 = (const float*)d_in[4];
    const float* dn_b2 = (const float*)d_in[5];
    const float* q_W1  = (const float*)d_in[6];
    const float* q_b1  = (const float*)d_in[7];
    const float* q_W2  = (const float*)d_in[8];
    const float* q_b2  = (const float*)d_in[9];
    const float* e_Win = (const float*)d_in[10];
    const float* e_bin = (const float*)d_in[11];
    const float* Wq    = (const float*)d_in[12];
    const float* Wk    = (const float*)d_in[13];
    const float* Wv    = (const float*)d_in[14];
    const float* Wo    = (const float*)d_in[15];
    const float* bq    = (const float*)d_in[16];
    const float* bk    = (const float*)d_in[17];
    const float* bv    = (const float*)d_in[18];
    const float* bo    = (const float*)d_in[19];
    const float* ln1_g = (const float*)d_in[20];
    const float* ln1_b = (const float*)d_in[21];
    const float* ln2_g = (const float*)d_in[22];
    const float* ln2_b = (const float*)d_in[23];
    const float* f_W1  = (const float*)d_in[24];
    const float* f_b1  = (const float*)d_in[25];
    const float* f_W2  = (const float*)d_in[26];
    const float* f_b2  = (const float*)d_in[27];
    const float* ci_T  = (const float*)d_in[28];
    const float* ci_G  = (const float*)d_in[29];
    const int*   interact = (const int*)d_in[30];
    (void)in_sizes; (void)n_in; (void)ws_size; (void)out_size;

    float* out = (float*)d_out;
    float* ws = (float*)d_ws;
    size_t off = 0;
    auto af32 = [&](size_t n) { float* p = ws + off; off += n; return p; };
    auto ab16 = [&](size_t n) { __bf16* p = (__bf16*)(ws + off); off += (n + 1) / 2; return p; };

    float*  S        = af32((size_t)NC * NC);      // scores / gram (fp32)
    float*  denoised = af32((size_t)NC * GG);
    __bf16* simB     = ab16((size_t)NC * NC);      // sim bf16; reused as S2 in CI
    __bf16* T1b      = ab16((size_t)NC * FF);
    float*  Tq       = af32((size_t)NC * 64);
    float*  quality  = af32(NC);
    float*  h        = af32((size_t)NC * DM);
    __bf16* hb       = ab16((size_t)NC * DM);
    __bf16* qbB      = ab16((size_t)NC * DM);
    __bf16* kbB      = ab16((size_t)NC * DM);
    float*  vb       = af32((size_t)NC * DM);
    float*  ob       = af32((size_t)NC * DM);
    __bf16* obB      = ab16((size_t)NC * DM);
    float*  t2       = af32((size_t)NC * DM);
    __bf16* rawB     = ab16((size_t)NC * GG);
    __bf16* denT     = ab16((size_t)GG * NC);      // denoised^T
    __bf16* smoT     = ab16((size_t)GG * NC);      // smoothed^T (CI only)
    __bf16* Ub       = ab16((size_t)NC * GG);
    __bf16* TembB    = ab16((size_t)NC * DM);
    float*  sqbuf    = af32(NC);
    __bf16* dnW1T    = ab16((size_t)FF * GG);
    __bf16* dnW2T    = ab16((size_t)GG * FF);
    __bf16* eWinT    = ab16((size_t)DM * GG);
    __bf16* WqT      = ab16((size_t)LL * DM * DM);
    __bf16* WkT      = ab16((size_t)LL * DM * DM);
    __bf16* WvT      = ab16((size_t)LL * DM * DM);
    __bf16* WoT      = ab16((size_t)LL * DM * DM);
    __bf16* fW1T     = ab16((size_t)LL * FF * DM);
    __bf16* fW2T     = ab16((size_t)LL * DM * FF);
    __bf16* ciTT     = ab16((size_t)NHCI * DM * DM);
    __bf16* ciGT     = ab16((size_t)NHCI * GG * GG);

    const float inv_sqrt_hd = 0.17677669529663687f;

    // ---- weight transposes / input conversion ----
    tc(dn_W1, dnW1T, GG, FF, nullptr, stream);
    tc(dn_W2, dnW2T, FF, GG, nullptr, stream);
    tc(e_Win, eWinT, GG, DM, nullptr, stream);
    for (int l = 0; l < LL; ++l) {
        tc(Wq + (size_t)l*DM*DM, WqT + (size_t)l*DM*DM, DM, DM, nullptr, stream);
        tc(Wk + (size_t)l*DM*DM, WkT + (size_t)l*DM*DM, DM, DM, nullptr, stream);
        tc(Wv + (size_t)l*DM*DM, WvT + (size_t)l*DM*DM, DM, DM, nullptr, stream);
        tc(Wo + (size_t)l*DM*DM, WoT + (size_t)l*DM*DM, DM, DM, nullptr, stream);
        tc(f_W1 + (size_t)l*DM*FF, fW1T + (size_t)l*FF*DM, DM, FF, nullptr, stream);
        tc(f_W2 + (size_t)l*FF*DM, fW2T + (size_t)l*DM*FF, FF, DM, nullptr, stream);
    }
    conv_k<<<(NC*GG/4 + 255)/256, 256, 0, stream>>>(raw, rawB, NC*GG/4);

    // ---- CellDenoise ----
    mg(MM_RELU_B16, rawB, GG, dnW1T, GG, dn_b1, nullptr, 0,
       nullptr, T1b, FF, NC, FF, GG, 1.f, nullptr, nullptr, stream);
    mg(MM_BIASRES, T1b, FF, dnW2T, FF, dn_b2, raw, GG,
       denoised, nullptr, GG, NC, GG, FF, 1.f, nullptr, nullptr, stream);
    // ---- CellQualify (fp32) ----
    gemm_k<E_TANH><<<dim3(1,32), 256, 0, stream>>>(raw, GG, q_W1, 64, q_b1, Tq, 64, NC, 64, GG, 1.f);
    qualify2_k<<<NC, 64, 0, stream>>>(Tq, q_W2, q_b2, quality);
    // ---- CellEmbed input proj ----
    mg(MM_BIAS_BOTH, rawB, GG, eWinT, GG, e_bin, nullptr, 0,
       h, hb, DM, NC, DM, GG, 1.f, nullptr, nullptr, stream);
    // ---- Transformer layers ----
    for (int l = 0; l < LL; ++l) {
        mg(MM_BIAS_B16, hb, DM, WqT + (size_t)l*DM*DM, DM, bq + l*DM, nullptr, 0,
           nullptr, qbB, DM, NC, DM, DM, 1.f, nullptr, nullptr, stream);
        mg(MM_BIAS_B16, hb, DM, WkT + (size_t)l*DM*DM, DM, bk + l*DM, nullptr, 0,
           nullptr, kbB, DM, NC, DM, DM, 1.f, nullptr, nullptr, stream);
        mg(MM_BIAS, hb, DM, WvT + (size_t)l*DM*DM, DM, bv + l*DM, nullptr, 0,
           vb, nullptr, DM, NC, DM, DM, 1.f, nullptr, nullptr, stream);
        for (int hd = 0; hd < 4; ++hd) {
            mg(MM_NONE, qbB + hd*HDIM, DM, kbB + hd*HDIM, DM, nullptr, nullptr, 0,
               S, nullptr, NC, NC, NC, HDIM, inv_sqrt_hd, nullptr, nullptr, stream);
            softmax_rows_k<<<NC, 256, 0, stream>>>(S, NC);
            gemm_k<E_NONE><<<dim3(1,32), 256, 0, stream>>>(S, NC, vb + hd*HDIM, DM, nullptr,
                                                           ob + hd*HDIM, DM, NC, HDIM, NC, 1.f);
        }
        conv_k<<<(NC*DM/4 + 255)/256, 256, 0, stream>>>(ob, obB, NC*DM/4);
        mg(MM_BIAS, obB, DM, WoT + (size_t)l*DM*DM, DM, bo + l*DM, nullptr, 0,
           t2, nullptr, DM, NC, DM, DM, 1.f, nullptr, nullptr, stream);
        add_ln_k<<<NC, 64, 0, stream>>>(h, hb, t2, ln1_g + l*DM, ln1_b + l*DM);
        mg(MM_RELU_B16, hb, DM, fW1T + (size_t)l*FF*DM, DM, f_b1 + l*FF, nullptr, 0,
           nullptr, T1b, FF, NC, FF, DM, 1.f, nullptr, nullptr, stream);
        mg(MM_BIAS, T1b, FF, fW2T + (size_t)l*DM*FF, FF, f_b2 + l*DM, nullptr, 0,
           t2, nullptr, DM, NC, DM, FF, 1.f, nullptr, nullptr, stream);
        add_ln_k<<<NC, 64, 0, stream>>>(h, hb, t2, ln2_g + l*DM, ln2_b + l*DM);
    }
    // ---- CellSmooth ----
    rownorm_k<<<NC, 64, 0, stream>>>(h, sqbuf);
    mg(MM_NONE, hb, DM, hb, DM, nullptr, nullptr, 0,
       S, nullptr, NC, NC, NC, DM, 1.f, nullptr, nullptr, stream);
    dist_softmax_k<<<NC, 256, 0, stream>>>(S, sqbuf, quality, simB, NC);
    tc(denoised, denT, NC, GG, nullptr, stream);
    mg(MM_NONE, simB, NC, denT, NC, nullptr, nullptr, 0,
       out, nullptr, GG, NC, GG, NC, 1.f, nullptr, nullptr, stream);   // out = smoothed
    // ---- CellInteract (gated on *interact) ----
    tc(out, smoT, NC, GG, interact, stream);
    for (int hh = 0; hh < NHCI; ++hh) {
        tc(ci_T + (size_t)hh*DM*DM, ciTT + (size_t)hh*DM*DM, DM, DM, interact, stream);
        tc(ci_G + (size_t)hh*GG*GG, ciGT + (size_t)hh*GG*GG, GG, GG, interact, stream);
    }
    for (int hh = 0; hh < NHCI; ++hh) {
        mg(MM_B16, hb, DM, ciTT + (size_t)hh*DM*DM, DM, nullptr, nullptr, 0,
           nullptr, TembB, DM, NC, DM, DM, 1.f, nullptr, interact, stream);
        mg(MM_SIGSP_B16, TembB, DM, hb, DM, nullptr, nullptr, 0,
           nullptr, simB, NC, NC, NC, DM, 1.f, spd, interact, stream);  // simB = spatial*sigmoid
        mg(MM_B16, simB, NC, smoT, NC, nullptr, nullptr, 0,
           nullptr, Ub, GG, NC, GG, NC, 1.f, nullptr, interact, stream);
        mg(MM_ACC, Ub, GG, ciGT + (size_t)hh*GG*GG, GG, nullptr, nullptr, 0,
           out, nullptr, GG, NC, GG, GG, 1.0f/1024.f, nullptr, interact, stream);
    }
}

// Round 3
// 916.532 us; speedup vs baseline: 13.1906x; 8.5931x over previous
//
#include <hip/hip_runtime.h>
#include <hip/hip_bf16.h>

#define NC 4096
#define GG 1024
#define DM 128
#define HDIM 32
#define FF 512
#define LL 2
#define NHCI 2
#define LS2 (100.0f*100.0f)

typedef __bf16 bf16x8 __attribute__((ext_vector_type(8)));
typedef __bf16 bf16x4 __attribute__((ext_vector_type(4)));
typedef float  f32x4  __attribute__((ext_vector_type(4)));

// ================= bf16 MFMA GEMM (m97 structure) =================
// C[M][N] = A[M][K](bf16,row-major) x BT[N][K](bf16,row-major)^T, fp32 accum.
// Tile 128x128, BK=32, 4 waves (2x2), wave tile 64x64 = 4x4 fragments of 16x16x32.
enum { MM_NONE=0, MM_BIAS, MM_BIAS_BOTH, MM_BIAS_B16, MM_RELU_B16, MM_B16,
       MM_BIASRES, MM_SIGSP_B16, MM_ACC, MM_TANH };

template<int EM>
__launch_bounds__(256)
__global__ void mgemm_k(const __bf16* __restrict__ A, int lda,
                        const __bf16* __restrict__ BT, int ldb,
                        const float* __restrict__ bias,
                        const float* __restrict__ res, int ldres,
                        float* __restrict__ C, __bf16* __restrict__ Cb, int ldc,
                        int M, int N, int K, float alpha,
                        const float* __restrict__ spd,
                        const int* __restrict__ flag)
{
    if (flag && *flag == 0) return;
    __shared__ __align__(16) __bf16 As[128][32];   // 8 KB
    __shared__ __align__(16) __bf16 Bs[128][32];   // 8 KB
    const int tid  = threadIdx.x;
    const int lane = tid & 63;
    const int wid  = tid >> 6;
    const int wm = wid >> 1, wn = wid & 1;
    const int bm = blockIdx.y * 128, bn = blockIdx.x * 128;

    f32x4 acc[4][4];
    #pragma unroll
    for (int m=0;m<4;m++)
        #pragma unroll
        for (int n=0;n<4;n++) acc[m][n] = (f32x4){0.f,0.f,0.f,0.f};

    const int c0 = wid*64 + lane, c1 = c0 + 256;
    const __bf16* ga0 = A  + (size_t)(bm + (c0>>2))*lda + ((c0&3)<<3);
    const __bf16* ga1 = A  + (size_t)(bm + (c1>>2))*lda + ((c1&3)<<3);
    const __bf16* gb0 = BT + (size_t)(bn + (c0>>2))*ldb + ((c0&3)<<3);
    const __bf16* gb1 = BT + (size_t)(bn + (c1>>2))*ldb + ((c1&3)<<3);
    auto* lA = (__attribute__((address_space(3))) __bf16*)&As[0][0];
    auto* lB = (__attribute__((address_space(3))) __bf16*)&Bs[0][0];
    auto* lA0 = (__attribute__((address_space(3))) void*)(lA + (size_t)(wid*64)*8);
    auto* lA1 = (__attribute__((address_space(3))) void*)(lA + (size_t)(256 + wid*64)*8);
    auto* lB0 = (__attribute__((address_space(3))) void*)(lB + (size_t)(wid*64)*8);
    auto* lB1 = (__attribute__((address_space(3))) void*)(lB + (size_t)(256 + wid*64)*8);

    const int r  = lane & 15;
    const int kb = lane >> 4;
    const int arow = wm*64, brow = wn*64;

    for (int k0 = 0; k0 < K; k0 += 32) {
        __builtin_amdgcn_global_load_lds((const __attribute__((address_space(1))) void*)ga0, lA0, 16, 0, 0);
        __builtin_amdgcn_global_load_lds((const __attribute__((address_space(1))) void*)ga1, lA1, 16, 0, 0);
        __builtin_amdgcn_global_load_lds((const __attribute__((address_space(1))) void*)gb0, lB0, 16, 0, 0);
        __builtin_amdgcn_global_load_lds((const __attribute__((address_space(1))) void*)gb1, lB1, 16, 0, 0);
        ga0 += 32; ga1 += 32; gb0 += 32; gb1 += 32;
        __syncthreads();
        bf16x8 af[4], bfr[4];
        #pragma unroll
        for (int m=0;m<4;m++) af[m]  = *(const bf16x8*)&As[arow + m*16 + r][kb*8];
        #pragma unroll
        for (int n=0;n<4;n++) bfr[n] = *(const bf16x8*)&Bs[brow + n*16 + r][kb*8];
        #pragma unroll
        for (int m=0;m<4;m++)
            #pragma unroll
            for (int n=0;n<4;n++)
                acc[m][n] = __builtin_amdgcn_mfma_f32_16x16x32_bf16(af[m], bfr[n], acc[m][n], 0, 0, 0);
        __syncthreads();
    }

    const int crow = (lane >> 4) * 4;
    const int ccol = lane & 15;
    #pragma unroll
    for (int m=0;m<4;m++) {
        #pragma unroll
        for (int n=0;n<4;n++) {
            const int gn = bn + wn*64 + n*16 + ccol;
            #pragma unroll
            for (int q=0;q<4;q++) {
                const int gm = bm + wm*64 + m*16 + crow + q;
                float v = acc[m][n][q] * alpha;
                if (EM==MM_BIAS || EM==MM_BIAS_BOTH || EM==MM_BIAS_B16 ||
                    EM==MM_RELU_B16 || EM==MM_BIASRES) v += bias[gn];
                if (EM==MM_TANH)     v = tanhf(v + bias[gn]);
                if (EM==MM_RELU_B16) v = fmaxf(v, 0.f);
                if (EM==MM_BIASRES)  v += res[(size_t)gm*ldres + gn];
                if (EM==MM_SIGSP_B16) {
                    v = 1.f/(1.f + __expf(-v));
                    v *= __expf(spd[(size_t)gm*(size_t)N + gn] * (-1.f/LS2));
                }
                const size_t ci = (size_t)gm*ldc + gn;
                if (EM==MM_ACC) C[ci] += v;
                else if (EM==MM_NONE || EM==MM_BIAS || EM==MM_BIASRES || EM==MM_TANH) C[ci] = v;
                else if (EM==MM_BIAS_BOTH) { C[ci] = v; Cb[ci] = (__bf16)v; }
                else Cb[ci] = (__bf16)v;
            }
        }
    }
}

// ================= fused flash attention =================
// Q,K bf16 [NC][DM] (head hd in cols hd*32..), VT bf16 [DM][NC] (transposed),
// O bf16 [NC][DM]. Per block: 4 waves x 16 Q-rows, head = blockIdx.y.
__launch_bounds__(256)
__global__ void flash_k(const __bf16* __restrict__ Q, const __bf16* __restrict__ Kb,
                        const __bf16* __restrict__ VT, __bf16* __restrict__ O)
{
    __shared__ __align__(16) __bf16 Plds[4][16][72];   // per-wave P tile [16 q][64 k]
    const int lane = threadIdx.x & 63, w = threadIdx.x >> 6;
    const int hd = blockIdx.y;
    const int q0 = blockIdx.x * 64 + w * 16;
    const int c  = lane & 15, kb = lane >> 4;
    const float scale = 0.17677669529663687f;   // 1/sqrt(32)

    const bf16x8 aq = *(const bf16x8*)&Q[(size_t)(q0 + c)*DM + hd*HDIM + kb*8];
    float m[4], l[4];
    #pragma unroll
    for (int q=0;q<4;q++) { m[q] = -3.0e38f; l[q] = 0.f; }
    f32x4 oacc[2] = {(f32x4){0,0,0,0}, (f32x4){0,0,0,0}};

    for (int kv = 0; kv < NC; kv += 64) {
        f32x4 s[4];
        #pragma unroll
        for (int n=0;n<4;n++) {
            bf16x8 bk = *(const bf16x8*)&Kb[(size_t)(kv + n*16 + c)*DM + hd*HDIM + kb*8];
            s[n] = __builtin_amdgcn_mfma_f32_16x16x32_bf16(aq, bk, (f32x4){0,0,0,0}, 0, 0, 0);
        }
        float f[4];
        #pragma unroll
        for (int q=0;q<4;q++) {
            float t = fmaxf(fmaxf(s[0][q], s[1][q]), fmaxf(s[2][q], s[3][q]));
            #pragma unroll
            for (int o=1;o<16;o<<=1) t = fmaxf(t, __shfl_xor(t, o));
            float nm = fmaxf(m[q], t * scale);
            f[q] = __expf(m[q] - nm);
            m[q] = nm;
        }
        float psum[4] = {0.f,0.f,0.f,0.f};
        #pragma unroll
        for (int n=0;n<4;n++) {
            #pragma unroll
            for (int q=0;q<4;q++) {
                float p = __expf(s[n][q]*scale - m[q]);
                psum[q] += p;
                Plds[w][kb*4+q][n*16+c] = (__bf16)p;
            }
        }
        #pragma unroll
        for (int q=0;q<4;q++) {
            float t = psum[q];
            #pragma unroll
            for (int o=1;o<16;o<<=1) t += __shfl_xor(t, o);
            l[q] = l[q]*f[q] + t;
            oacc[0][q] *= f[q];
            oacc[1][q] *= f[q];
        }
        #pragma unroll
        for (int ks=0;ks<2;ks++) {
            bf16x8 ap = *(const bf16x8*)&Plds[w][c][ks*32 + kb*8];
            #pragma unroll
            for (int n2=0;n2<2;n2++) {
                bf16x8 bv = *(const bf16x8*)&VT[(size_t)(hd*HDIM + n2*16 + c)*NC + kv + ks*32 + kb*8];
                oacc[n2] = __builtin_amdgcn_mfma_f32_16x16x32_bf16(ap, bv, oacc[n2], 0, 0, 0);
            }
        }
    }
    #pragma unroll
    for (int n2=0;n2<2;n2++)
        #pragma unroll
        for (int q=0;q<4;q++)
            O[(size_t)(q0 + kb*4 + q)*DM + hd*HDIM + n2*16 + c] = (__bf16)(oacc[n2][q] / l[q]);
}

// ================= small kernels =================
__global__ void qualify2_k(const float* __restrict__ Tq, const float* __restrict__ w,
                           const float* __restrict__ b2, float* __restrict__ quality)
{
    int row = blockIdx.x, lane = threadIdx.x;
    float v = Tq[row*128 + lane] * w[lane];
    #pragma unroll
    for (int o=32;o>0;o>>=1) v += __shfl_down(v, o);
    if (lane == 0) quality[row] = v + b2[0];
}

__global__ void qw1pad_k(const float* __restrict__ W, __bf16* __restrict__ out)
{
    int idx = blockIdx.x*256 + threadIdx.x;   // 128*1024
    int k = idx & 1023, j = idx >> 10;
    out[(size_t)j*GG + k] = (j < 64) ? (__bf16)W[(size_t)k*64 + j] : (__bf16)0.f;
}

__global__ void padb_k(const float* __restrict__ b, float* __restrict__ out)
{
    int i = threadIdx.x;
    out[i] = (i < 64) ? b[i] : 0.f;
}

__global__ void rownorm_k(const float* __restrict__ h, float* __restrict__ sq)
{
    int row = blockIdx.x, lane = threadIdx.x;
    float x0 = h[row*DM + lane], x1 = h[row*DM + lane + 64];
    float v = x0*x0 + x1*x1;
    #pragma unroll
    for (int o=32;o>0;o>>=1) v += __shfl_down(v, o);
    if (lane == 0) sq[row] = v;
}

__global__ void add_ln_k(float* __restrict__ h, __bf16* __restrict__ hb,
                         const float* __restrict__ t,
                         const float* __restrict__ g, const float* __restrict__ b)
{
    int row = blockIdx.x, lane = threadIdx.x;
    float x0 = h[row*DM + lane]      + t[row*DM + lane];
    float x1 = h[row*DM + lane + 64] + t[row*DM + lane + 64];
    float s = x0 + x1, ss = x0*x0 + x1*x1;
    #pragma unroll
    for (int o=32;o>0;o>>=1) { s += __shfl_down(s, o); ss += __shfl_down(ss, o); }
    s = __shfl(s, 0); ss = __shfl(ss, 0);
    float mean = s * (1.f/128.f);
    float var  = ss * (1.f/128.f) - mean*mean;
    float inv  = rsqrtf(var + 1e-5f);
    float y0 = g[lane]      * (x0 - mean) * inv + b[lane];
    float y1 = g[lane + 64] * (x1 - mean) * inv + b[lane + 64];
    h[row*DM + lane]       = y0;  h[row*DM + lane + 64]  = y1;
    hb[row*DM + lane]      = (__bf16)y0;
    hb[row*DM + lane + 64] = (__bf16)y1;
}

__launch_bounds__(256)
__global__ void dist_softmax_k(const float* __restrict__ Sg, const float* __restrict__ sqv,
                               const float* __restrict__ qual, __bf16* __restrict__ P, int W)
{
    __shared__ float sm[4], sl[4];
    size_t row = blockIdx.x;
    const float* p = Sg + row * (size_t)W;
    __bf16* po = P + row * (size_t)W;
    int tid = threadIdx.x;
    float sqi = sqv[row];
    float m = -3.0e38f, l = 0.f;
    for (int j = tid; j < W; j += 256) {
        float d2 = fmaxf(sqi + sqv[j] - 2.f * p[j], 0.f);
        float lg = -sqrtf(d2) + qual[j];
        float mn = fmaxf(m, lg);
        l = l * __expf(m - mn) + __expf(lg - mn);
        m = mn;
    }
    #pragma unroll
    for (int o=32;o>0;o>>=1) {
        float m2 = __shfl_down(m, o), l2 = __shfl_down(l, o);
        float mn = fmaxf(m, m2);
        l = l * __expf(m - mn) + l2 * __expf(m2 - mn);
        m = mn;
    }
    if ((tid & 63) == 0) { sm[tid>>6] = m; sl[tid>>6] = l; }
    __syncthreads();
    m = sm[0]; l = sl[0];
    #pragma unroll
    for (int i=1;i<4;i++) {
        float mn = fmaxf(m, sm[i]);
        l = l * __expf(m - mn) + sl[i] * __expf(sm[i] - mn);
        m = mn;
    }
    float inv = 1.f / l;
    for (int j = tid; j < W; j += 256) {
        float d2 = fmaxf(sqi + sqv[j] - 2.f * p[j], 0.f);
        float lg = -sqrtf(d2) + qual[j];
        po[j] = (__bf16)(__expf(lg - m) * inv);
    }
}

__global__ void tconv_k(const float* __restrict__ in, __bf16* __restrict__ out,
                        int R, int C, const int* __restrict__ flag)
{
    if (flag && *flag == 0) return;
    __shared__ float tile[32][33];
    int bc = blockIdx.x * 32, br = blockIdx.y * 32;
    int tx = threadIdx.x & 31, ty = threadIdx.x >> 5;
    #pragma unroll
    for (int i=0;i<4;i++)
        tile[ty + 8*i][tx] = in[(size_t)(br + ty + 8*i)*C + bc + tx];
    __syncthreads();
    #pragma unroll
    for (int i=0;i<4;i++)
        out[(size_t)(bc + ty + 8*i)*R + br + tx] = (__bf16)tile[tx][ty + 8*i];
}

__global__ void conv_k(const float* __restrict__ in, __bf16* __restrict__ out, int n4)
{
    int i = blockIdx.x * 256 + threadIdx.x;
    if (i < n4) {
        float4 v = ((const float4*)in)[i];
        bf16x4 o = {(__bf16)v.x, (__bf16)v.y, (__bf16)v.z, (__bf16)v.w};
        ((bf16x4*)out)[i] = o;
    }
}

// ================= launchers =================
static void mg(int em, const __bf16* A, int lda, const __bf16* BT, int ldb,
               const float* bias, const float* res, int ldres,
               float* C, __bf16* Cb, int ldc, int M, int N, int K, float alpha,
               const float* spd, const int* flag, hipStream_t s)
{
    dim3 grid(N/128, M/128), block(256);
#define MGL(E) mgemm_k<E><<<grid,block,0,s>>>(A,lda,BT,ldb,bias,res,ldres,C,Cb,ldc,M,N,K,alpha,spd,flag)
    switch (em) {
        case MM_NONE:      MGL(MM_NONE);      break;
        case MM_BIAS:      MGL(MM_BIAS);      break;
        case MM_BIAS_BOTH: MGL(MM_BIAS_BOTH); break;
        case MM_BIAS_B16:  MGL(MM_BIAS_B16);  break;
        case MM_RELU_B16:  MGL(MM_RELU_B16);  break;
        case MM_B16:       MGL(MM_B16);       break;
        case MM_BIASRES:   MGL(MM_BIASRES);   break;
        case MM_SIGSP_B16: MGL(MM_SIGSP_B16); break;
        case MM_ACC:       MGL(MM_ACC);       break;
        case MM_TANH:      MGL(MM_TANH);      break;
    }
#undef MGL
}

static void tc(const float* in, __bf16* out, int R, int C, const int* flag, hipStream_t s)
{
    dim3 grid(C/32, R/32), block(256);
    tconv_k<<<grid, block, 0, s>>>(in, out, R, C, flag);
}

extern "C" void kernel_launch(void* const* d_in, const int* in_sizes, int n_in,
                              void* d_out, int out_size, void* d_ws, size_t ws_size,
                              hipStream_t stream)
{
    const float* raw   = (const float*)d_in[0];
    const float* spd   = (const float*)d_in[1];
    const float* dn_W1 = (const float*)d_in[2];
    const float* dn_b1 = (const float*)d_in[3];
    const float* dn_W2 = (const float*)d_in[4];
    const float* dn_b2 = (const float*)d_in[5];
    const float* q_W1  = (const float*)d_in[6];
    const float* q_b1  = (const float*)d_in[7];
    const float* q_W2  = (const float*)d_in[8];
    const float* q_b2  = (const float*)d_in[9];
    const float* e_Win = (const float*)d_in[10];
    const float* e_bin = (const float*)d_in[11];
    const float* Wq    = (const float*)d_in[12];
    const float* Wk    = (const float*)d_in[13];
    const float* Wv    = (const float*)d_in[14];
    const float* Wo    = (const float*)d_in[15];
    const float* bq    = (const float*)d_in[16];
    const float* bk    = (const float*)d_in[17];
    const float* bv    = (const float*)d_in[18];
    const float* bo    = (const float*)d_in[19];
    const float* ln1_g = (const float*)d_in[20];
    const float* ln1_b = (const float*)d_in[21];
    const float* ln2_g = (const float*)d_in[22];
    const float* ln2_b = (const float*)d_in[23];
    const float* f_W1  = (const float*)d_in[24];
    const float* f_b1  = (const float*)d_in[25];
    const float* f_W2  = (const float*)d_in[26];
    const float* f_b2  = (const float*)d_in[27];
    const float* ci_T  = (const float*)d_in[28];
    const float* ci_G  = (const float*)d_in[29];
    const int*   interact = (const int*)d_in[30];
    (void)in_sizes; (void)n_in; (void)ws_size; (void)out_size;

    float* out = (float*)d_out;
    float* ws = (float*)d_ws;
    size_t off = 0;
    auto af32 = [&](size_t n) { float* p = ws + off; off += n; return p; };
    auto ab16 = [&](size_t n) { __bf16* p = (__bf16*)(ws + off); off += (n + 1) / 2; return p; };

    float*  S        = af32((size_t)NC * NC);
    float*  denoised = af32((size_t)NC * GG);
    __bf16* simB     = ab16((size_t)NC * NC);
    __bf16* T1b      = ab16((size_t)NC * FF);
    float*  Tq       = af32((size_t)NC * 128);
    float*  quality  = af32(NC);
    float*  h        = af32((size_t)NC * DM);
    __bf16* hb       = ab16((size_t)NC * DM);
    __bf16* qbB      = ab16((size_t)NC * DM);
    __bf16* kbB      = ab16((size_t)NC * DM);
    float*  vb       = af32((size_t)NC * DM);
    __bf16* vbT      = ab16((size_t)DM * NC);
    __bf16* obB      = ab16((size_t)NC * DM);
    float*  t2       = af32((size_t)NC * DM);
    __bf16* rawB     = ab16((size_t)NC * GG);
    __bf16* denT     = ab16((size_t)GG * NC);
    __bf16* smoT     = ab16((size_t)GG * NC);
    __bf16* Ub       = ab16((size_t)NC * GG);
    __bf16* TembB    = ab16((size_t)NC * DM);
    float*  sqbuf    = af32(NC);
    __bf16* dnW1T    = ab16((size_t)FF * GG);
    __bf16* dnW2T    = ab16((size_t)GG * FF);
    __bf16* eWinT    = ab16((size_t)DM * GG);
    __bf16* qW1pT    = ab16((size_t)128 * GG);
    float*  qb1p     = af32(128);
    __bf16* WqT      = ab16((size_t)LL * DM * DM);
    __bf16* WkT      = ab16((size_t)LL * DM * DM);
    __bf16* WvT      = ab16((size_t)LL * DM * DM);
    __bf16* WoT      = ab16((size_t)LL * DM * DM);
    __bf16* fW1T     = ab16((size_t)LL * FF * DM);
    __bf16* fW2T     = ab16((size_t)LL * DM * FF);
    __bf16* ciTT     = ab16((size_t)NHCI * DM * DM);
    __bf16* ciGT     = ab16((size_t)NHCI * GG * GG);

    tc(dn_W1, dnW1T, GG, FF, nullptr, stream);
    tc(dn_W2, dnW2T, FF, GG, nullptr, stream);
    tc(e_Win, eWinT, GG, DM, nullptr, stream);
    qw1pad_k<<<(128*GG)/256, 256, 0, stream>>>(q_W1, qW1pT);
    padb_k<<<1, 128, 0, stream>>>(q_b1, qb1p);
    for (int l = 0; l < LL; ++l) {
        tc(Wq + (size_t)l*DM*DM, WqT + (size_t)l*DM*DM, DM, DM, nullptr, stream);
        tc(Wk + (size_t)l*DM*DM, WkT + (size_t)l*DM*DM, DM, DM, nullptr, stream);
        tc(Wv + (size_t)l*DM*DM, WvT + (size_t)l*DM*DM, DM, DM, nullptr, stream);
        tc(Wo + (size_t)l*DM*DM, WoT + (size_t)l*DM*DM, DM, DM, nullptr, stream);
        tc(f_W1 + (size_t)l*DM*FF, fW1T + (size_t)l*FF*DM, DM, FF, nullptr, stream);
        tc(f_W2 + (size_t)l*FF*DM, fW2T + (size_t)l*DM*FF, FF, DM, nullptr, stream);
    }
    conv_k<<<(NC*GG/4 + 255)/256, 256, 0, stream>>>(raw, rawB, NC*GG/4);

    // CellDenoise
    mg(MM_RELU_B16, rawB, GG, dnW1T, GG, dn_b1, nullptr, 0,
       nullptr, T1b, FF, NC, FF, GG, 1.f, nullptr, nullptr, stream);
    mg(MM_BIASRES, T1b, FF, dnW2T, FF, dn_b2, raw, GG,
       denoised, nullptr, GG, NC, GG, FF, 1.f, nullptr, nullptr, stream);
    // CellQualify (MFMA, padded to N=128)
    mg(MM_TANH, rawB, GG, qW1pT, GG, qb1p, nullptr, 0,
       Tq, nullptr, 128, NC, 128, GG, 1.f, nullptr, nullptr, stream);
    qualify2_k<<<NC, 64, 0, stream>>>(Tq, q_W2, q_b2, quality);
    // CellEmbed input proj
    mg(MM_BIAS_BOTH, rawB, GG, eWinT, GG, e_bin, nullptr, 0,
       h, hb, DM, NC, DM, GG, 1.f, nullptr, nullptr, stream);
    // Transformer layers with fused flash attention
    for (int l = 0; l < LL; ++l) {
        mg(MM_BIAS_B16, hb, DM, WqT + (size_t)l*DM*DM, DM, bq + l*DM, nullptr, 0,
           nullptr, qbB, DM, NC, DM, DM, 1.f, nullptr, nullptr, stream);
        mg(MM_BIAS_B16, hb, DM, WkT + (size_t)l*DM*DM, DM, bk + l*DM, nullptr, 0,
           nullptr, kbB, DM, NC, DM, DM, 1.f, nullptr, nullptr, stream);
        mg(MM_BIAS, hb, DM, WvT + (size_t)l*DM*DM, DM, bv + l*DM, nullptr, 0,
           vb, nullptr, DM, NC, DM, DM, 1.f, nullptr, nullptr, stream);
        tc(vb, vbT, NC, DM, nullptr, stream);
        flash_k<<<dim3(NC/64, 4), 256, 0, stream>>>(qbB, kbB, vbT, obB);
        mg(MM_BIAS, obB, DM, WoT + (size_t)l*DM*DM, DM, bo + l*DM, nullptr, 0,
           t2, nullptr, DM, NC, DM, DM, 1.f, nullptr, nullptr, stream);
        add_ln_k<<<NC, 64, 0, stream>>>(h, hb, t2, ln1_g + l*DM, ln1_b + l*DM);
        mg(MM_RELU_B16, hb, DM, fW1T + (size_t)l*FF*DM, DM, f_b1 + l*FF, nullptr, 0,
           nullptr, T1b, FF, NC, FF, DM, 1.f, nullptr, nullptr, stream);
        mg(MM_BIAS, T1b, FF, fW2T + (size_t)l*DM*FF, FF, f_b2 + l*DM, nullptr, 0,
           t2, nullptr, DM, NC, DM, FF, 1.f, nullptr, nullptr, stream);
        add_ln_k<<<NC, 64, 0, stream>>>(h, hb, t2, ln2_g + l*DM, ln2_b + l*DM);
    }
    // CellSmooth
    rownorm_k<<<NC, 64, 0, stream>>>(h, sqbuf);
    mg(MM_NONE, hb, DM, hb, DM, nullptr, nullptr, 0,
       S, nullptr, NC, NC, NC, DM, 1.f, nullptr, nullptr, stream);
    dist_softmax_k<<<NC, 256, 0, stream>>>(S, sqbuf, quality, simB, NC);
    tc(denoised, denT, NC, GG, nullptr, stream);
    mg(MM_NONE, simB, NC, denT, NC, nullptr, nullptr, 0,
       out, nullptr, GG, NC, GG, NC, 1.f, nullptr, nullptr, stream);
    // CellInteract (gated on *interact)
    tc(out, smoT, NC, GG, interact, stream);
    for (int hh = 0; hh < NHCI; ++hh) {
        tc(ci_T + (size_t)hh*DM*DM, ciTT + (size_t)hh*DM*DM, DM, DM, interact, stream);
        tc(ci_G + (size_t)hh*GG*GG, ciGT + (size_t)hh*GG*GG, GG, GG, interact, stream);
    }
    for (int hh = 0; hh < NHCI; ++hh) {
        mg(MM_B16, hb, DM, ciTT + (size_t)hh*DM*DM, DM, nullptr, nullptr, 0,
           nullptr, TembB, DM, NC, DM, DM, 1.f, nullptr, interact, stream);
        mg(MM_SIGSP_B16, TembB, DM, hb, DM, nullptr, nullptr, 0,
           nullptr, simB, NC, NC, NC, DM, 1.f, spd, interact, stream);
        mg(MM_B16, simB, NC, smoT, NC, nullptr, nullptr, 0,
           nullptr, Ub, GG, NC, GG, NC, 1.f, nullptr, interact, stream);
        mg(MM_ACC, Ub, GG, ciGT + (size_t)hh*GG*GG, GG, nullptr, nullptr, 0,
           out, nullptr, GG, NC, GG, GG, 1.0f/1024.f, nullptr, interact, stream);
    }
}